// Round 6
// baseline (202.135 us; speedup 1.0000x reference)
//
#include <hip/hip_runtime.h>
#include <hip/hip_bf16.h>

// GraphSAGE: out = normalize( [x, segsum(vals*x[cols], rows)] @ W^T + b )
// N=100000, E=1600000, IN_F=128, OUT_F=128.
//
// Round 10: int8 per-row-scaled gather payload (fp8 e4m3 failed absmax by
// 1.38x; int8+per-row scale has ~2.7x lower RMS err at the SAME 128 B/row).
// Per-source-row scale xs[c]=max|x_c|/127 folded into staged edge weight
// (w_e = val_e * xs[col_e]) -> zero inner-loop cost. Self half stays exact
// (fp32 -> bf16 RNE in phase 2, bit-identical to the passing bf16 pipeline).
// Tests both accuracy fix and the untested halved-gather-bytes hypothesis.
//
// ws layout:
//   [0    , ~400K)  row_ptr (int[N+1])
//   [448K , 512K)   Wf: fragment-major bf16 W, 4096 x 16B
//   [512K , 912K)   xs: per-row dequant scale (float[N])
//   [1M   , +12.8M) xq: int8 quantized x, N x 128 bytes (feature f at byte f)

typedef __bf16 bf16x8_t __attribute__((ext_vector_type(8)));
typedef float f32x4_t __attribute__((ext_vector_type(4)));
typedef float f32x2_t __attribute__((ext_vector_type(2)));
typedef unsigned int u32x2_t __attribute__((ext_vector_type(2)));

#define DESC_CAP 512   // max staged edges per block (mean 256, 16 sigma)
#define RING_D   8     // gather rows in flight per wave

__device__ __forceinline__ unsigned int f32_to_bf16(float f) {
    unsigned int u = __float_as_uint(f);
    unsigned int r = u + 0x7fffu + ((u >> 16) & 1u);   // RNE (no NaN inputs)
    return r >> 16;
}
__device__ __forceinline__ unsigned int pack2(float a, float b) {
    return f32_to_bf16(a) | (f32_to_bf16(b) << 16);
}

// --- K0: fused prep: x->int8 row-quant | rowptr | wcast --------------------
// xcast: 16 rows/block; 16 lanes per row (8 features/lane); row max via
// 16-lane shfl_xor reduce; q = rint(x*127/max); scale stored to xs[row].
__global__ void prep_kernel(const float* __restrict__ x, u32x2_t* __restrict__ xq,
                            float* __restrict__ xs,
                            const int* __restrict__ rows, int* __restrict__ row_ptr,
                            const float* __restrict__ W, uint4* __restrict__ Wf,
                            int Nn, int Ee, int xcast_blks, int rowptr_blks) {
    int blk = blockIdx.x;
    if (blk < xcast_blks) {
        int lane = threadIdx.x & 63;
        int wv   = threadIdx.x >> 6;
        int r    = blk * 16 + wv * 4 + (lane >> 4);
        int fc   = (lane & 15) * 8;
        if (r < Nn) {
            const f32x4_t* pf = (const f32x4_t*)(x + (size_t)r * 128 + fc);
            f32x4_t f0 = __builtin_nontemporal_load(pf);
            f32x4_t f1 = __builtin_nontemporal_load(pf + 1);
            float m = fmaxf(fmaxf(fmaxf(fabsf(f0.x), fabsf(f0.y)),
                                  fmaxf(fabsf(f0.z), fabsf(f0.w))),
                            fmaxf(fmaxf(fabsf(f1.x), fabsf(f1.y)),
                                  fmaxf(fabsf(f1.z), fabsf(f1.w))));
            m = fmaxf(m, __shfl_xor(m, 1, 64));
            m = fmaxf(m, __shfl_xor(m, 2, 64));
            m = fmaxf(m, __shfl_xor(m, 4, 64));
            m = fmaxf(m, __shfl_xor(m, 8, 64));
            float inv = (m > 0.f) ? 127.f / m : 0.f;
            int q0 = (int)rintf(f0.x * inv), q1 = (int)rintf(f0.y * inv);
            int q2 = (int)rintf(f0.z * inv), q3 = (int)rintf(f0.w * inv);
            int q4 = (int)rintf(f1.x * inv), q5 = (int)rintf(f1.y * inv);
            int q6 = (int)rintf(f1.z * inv), q7 = (int)rintf(f1.w * inv);
            u32x2_t o;
            o.x = (q0 & 255) | ((q1 & 255) << 8) | ((q2 & 255) << 16)
                | ((unsigned)(q3 & 255) << 24);
            o.y = (q4 & 255) | ((q5 & 255) << 8) | ((q6 & 255) << 16)
                | ((unsigned)(q7 & 255) << 24);
            __builtin_nontemporal_store(o, &xq[(size_t)r * 16 + (lane & 15)]);
            if ((lane & 15) == 0) xs[r] = m * (1.f / 127.f);
        }
    } else if (blk < xcast_blks + rowptr_blks) {
        int n = (blk - xcast_blks) * 256 + threadIdx.x;
        if (n <= Nn) {
            int lo = 0, hi = Ee;
            while (lo < hi) {
                int mid = (lo + hi) >> 1;
                if (rows[mid] < n) lo = mid + 1; else hi = mid;
            }
            row_ptr[n] = lo;
        }
    } else {
        int i = (blk - xcast_blks - rowptr_blks) * 256 + threadIdx.x;  // 0..4095
        int lane = i & 63, ks = (i >> 6) & 7, t = i >> 9;
        int row = t * 16 + (lane & 15);
        int col = ks * 32 + (lane >> 4) * 8;
        const float* p = W + (size_t)row * 256 + col;
        uint4 o;
        o.x = pack2(p[0], p[1]); o.y = pack2(p[2], p[3]);
        o.z = pack2(p[4], p[5]); o.w = pack2(p[6], p[7]);
        Wf[i] = o;                       // hot: every block re-reads -> cacheable
    }
}

// --- K1: fused agg + gemm + normalize --------------------------------------
// block = 256 thr = 4 waves, 16 nodes (grid 6250 exact).
// Phase 1 (agg): edges staged block-wide in LDS as {col|dest<<28, w} with
//   w = val * xs[col] (per-row dequant scale folded at stage time).
//   Wave w owns nodes 4w..4w+3 = contiguous edge range. Per edge: one
//   64-lane x 2B contiguous gather of the int8 source row (lane holds
//   features {2l,2l+1}); sext+cvt decode; f32 accumulate; flush to nbLDS
//   (pre-zeroed) on dest change. Ring of RING_D ushort loads.
// Phase 2 (gemm): 16 rows, K=256; self half read from fp32 x and RNE-packed
//   to bf16 (exact, bit-identical to bf16 pipeline); neighbor half from
//   nbLDS; 8 col-tiles split 2/wave; MFMA 16x16x32 bf16; cross-wave norm
//   reduction through LDS; fused bias+normalize NT store.
__global__ void __launch_bounds__(256, 6)
fused_kernel(const int* __restrict__ row_ptr,
             const int* __restrict__ cols,
             const float* __restrict__ vals,
             const float* __restrict__ x,
             const float* __restrict__ xs,
             const char* __restrict__ xqB,
             const bf16x8_t* __restrict__ Wf,
             const float* __restrict__ b,
             float* __restrict__ out, int Nn) {
    __shared__ int   rpS[17];
    __shared__ uint2 cvLDS[DESC_CAP];                     // 4 KB
    __shared__ uint4 nbLDS[16 * 17];                      // 4.25 KB
    __shared__ float __attribute__((aligned(16))) sqLDS[16][4];

    int lane = threadIdx.x & 63;
    int w    = threadIdx.x >> 6;
    int r0   = blockIdx.x * 16;

    if (threadIdx.x < 17)
        rpS[threadIdx.x] = row_ptr[min(r0 + (int)threadIdx.x, Nn)];
    __syncthreads();

    int eLo = rpS[0], eHi = rpS[16];
    int cnt = eHi - eLo;
    bool big = cnt > DESC_CAP;     // block-uniform; ~never on this input

    if (!big) {
        for (int i = threadIdx.x; i < cnt; i += 256) {
            int e = eLo + i;
            int c = __builtin_nontemporal_load(&cols[e]);
            float v = __builtin_nontemporal_load(&vals[e]);
            float vw = v * xs[c];       // fold dequant scale (xs is L2-hot)
            // dest = largest d in [0,15] with rpS[d] <= e  (branchless bisect)
            int d = (e >= rpS[8]) ? 8 : 0;
            d += (e >= rpS[d + 4]) ? 4 : 0;
            d += (e >= rpS[d + 2]) ? 2 : 0;
            d += (e >= rpS[d + 1]) ? 1 : 0;
            uint2 cv;
            cv.x = (unsigned)c | ((unsigned)d << 28);     // c < 2^17
            cv.y = __float_as_uint(vw);
            cvLDS[i] = cv;
        }
    }
    {   // pre-zero nbLDS: deg-0 nodes stay zero
        unsigned* nz = (unsigned*)nbLDS;
        for (int i = threadIdx.x; i < 16 * 17 * 4; i += 256) nz[i] = 0u;
    }
    __syncthreads();

    // ---------------- phase 1: aggregate ----------------
    if (!big) {
        int wLo = __builtin_amdgcn_readfirstlane(rpS[w * 4]     - eLo);
        int wHi = __builtin_amdgcn_readfirstlane(rpS[w * 4 + 4] - eLo);
        int nEd = wHi - wLo;
        if (nEd > 0) {
            unsigned lane2 = (unsigned)lane << 1;         // 2B per lane
            int wHiM1 = wHi - 1;
            unsigned* nbW = (unsigned*)nbLDS;

            unsigned P[RING_D];                           // int8 pair per lane
            uint2    cv[RING_D];
#pragma unroll
            for (int d = 0; d < RING_D; ++d) {            // prologue (clamped)
                int kd = min(wLo + d, wHiM1);
                cv[d] = cvLDS[kd];
                unsigned voff = ((cv[d].x & 0x0FFFFFFFu) << 7) | lane2;
                P[d] = *(const unsigned short*)(xqB + voff);
            }
            int cur = (int)(cv[0].x >> 28);
            float ax = 0.f, ay = 0.f;

            int nit = (nEd + RING_D - 1) / RING_D;
            int k0 = wLo;
            for (int it = 0; it < nit; ++it, k0 += RING_D) {
#pragma unroll
                for (int d = 0; d < RING_D; ++d) {
                    int k = k0 + d;
                    uint2 cvk = cv[d];
                    int dk = (int)(cvk.x >> 28);
                    if (dk != cur) {                      // wave-uniform branch
                        nbW[cur * 68 + lane] = pack2(ax, ay);
                        ax = 0.f; ay = 0.f;
                        cur = dk;
                    }
                    float vv = (k < wHi) ? __uint_as_float(cvk.y) : 0.f;
                    unsigned Pd = P[d];                   // auto vmcnt wait
                    float fx = (float)(int)(signed char)(Pd & 0xffu);
                    float fy = (float)(int)(signed char)((Pd >> 8) & 0xffu);
                    ax += vv * fx;
                    ay += vv * fy;
                    uint2 cvn = cvLDS[min(k + RING_D, wHiM1)];
                    unsigned voff = ((cvn.x & 0x0FFFFFFFu) << 7) | lane2;
                    P[d] = *(const unsigned short*)(xqB + voff);
                    cv[d] = cvn;
                }
            }
            nbW[cur * 68 + lane] = pack2(ax, ay);         // final flush
        }
    } else {
        // oversized block: simple per-slot loop (safety net, ~never taken)
        int h = lane >> 4;            // node slot within wave
        int l = lane & 15;            // feature chunk [8l, 8l+8)
        int node = w * 4 + h;         // 0..15
        int n = r0 + node;
        int nn = min(n, Nn - 1);
        int start = row_ptr[nn], end = row_ptr[nn + 1];
        if (n >= Nn) end = start;
        unsigned loff = (unsigned)l << 3;                 // 8B per 16-lane slot

        f32x2_t a0 = {0.f, 0.f}, a1 = {0.f, 0.f}, a2 = {0.f, 0.f}, a3 = {0.f, 0.f};
        for (int e = start; e < end; ++e) {
            int   c = cols[e];
            float v = vals[e] * xs[c];
            uint2 p = *(const uint2*)(xqB + (((unsigned)c << 7) | loff));
            a0.x += v * (float)(int)(signed char)(p.x & 0xffu);
            a0.y += v * (float)(int)(signed char)((p.x >> 8) & 0xffu);
            a1.x += v * (float)(int)(signed char)((p.x >> 16) & 0xffu);
            a1.y += v * (float)(int)(signed char)(p.x >> 24);
            a2.x += v * (float)(int)(signed char)(p.y & 0xffu);
            a2.y += v * (float)(int)(signed char)((p.y >> 8) & 0xffu);
            a3.x += v * (float)(int)(signed char)((p.y >> 16) & 0xffu);
            a3.y += v * (float)(int)(signed char)(p.y >> 24);
        }
        uint4 o;
        o.x = pack2(a0.x, a0.y); o.y = pack2(a1.x, a1.y);
        o.z = pack2(a2.x, a2.y); o.w = pack2(a3.x, a3.y);
        nbLDS[node * 17 + l] = o;
    }
    __syncthreads();

    // ---------------- phase 2: gemm + normalize ----------------
    int m    = lane & 15;
    int quad = lane >> 4;

    int arow = min(r0 + m, Nn - 1);
    const float* xrow = x + (size_t)arow * 128;

    bf16x8_t a[8];
#pragma unroll
    for (int ks = 0; ks < 4; ++ks) {                      // self: fp32 -> bf16 RNE
        const f32x4_t* pf = (const f32x4_t*)(xrow + 32 * ks + 8 * quad);
        f32x4_t f0 = pf[0];
        f32x4_t f1 = pf[1];
        union { bf16x8_t v; unsigned u[4]; } au;
        au.u[0] = pack2(f0.x, f0.y); au.u[1] = pack2(f0.z, f0.w);
        au.u[2] = pack2(f1.x, f1.y); au.u[3] = pack2(f1.z, f1.w);
        a[ks] = au.v;
    }
#pragma unroll
    for (int ks = 0; ks < 4; ++ks)
        a[4 + ks] = *(const bf16x8_t*)&nbLDS[m * 17 + ks * 4 + quad];

    f32x4_t acc[2];
    float bc[2];
#pragma unroll
    for (int j = 0; j < 2; ++j) {
        int t = w * 2 + j;
        acc[j] = (f32x4_t){0.f, 0.f, 0.f, 0.f};
        bc[j]  = b[t * 16 + m];
#pragma unroll
        for (int ks = 0; ks < 8; ++ks) {
            acc[j] = __builtin_amdgcn_mfma_f32_16x16x32_bf16(
                a[ks], Wf[(t * 8 + ks) * 64 + lane], acc[j], 0, 0, 0);
        }
    }

    // per-row sum of squares: lane holds rows quad*4+r, cols (w*2+j)*16+m
    float sq[4] = {0.f, 0.f, 0.f, 0.f};
#pragma unroll
    for (int j = 0; j < 2; ++j)
#pragma unroll
        for (int r = 0; r < 4; ++r) {
            float u = acc[j][r] + bc[j];
            sq[r] += u * u;
        }
#pragma unroll
    for (int off = 1; off <= 8; off <<= 1) {
#pragma unroll
        for (int r = 0; r < 4; ++r) sq[r] += __shfl_xor(sq[r], off, 64);
    }
    if (m == 0) {
#pragma unroll
        for (int r = 0; r < 4; ++r) sqLDS[quad * 4 + r][w] = sq[r];
    }
    __syncthreads();

    float scale[4];
#pragma unroll
    for (int r = 0; r < 4; ++r) {
        const float4 q4 = *(const float4*)sqLDS[quad * 4 + r];
        float tot = q4.x + q4.y + q4.z + q4.w;
        scale[r] = 1.f / fmaxf(sqrtf(tot), 1e-12f);
    }

#pragma unroll
    for (int r = 0; r < 4; ++r) {
        int row = r0 + quad * 4 + r;
        if (row < Nn) {
            float* orow = out + (size_t)row * 128;
#pragma unroll
            for (int j = 0; j < 2; ++j) {
                int t = w * 2 + j;
                __builtin_nontemporal_store((acc[j][r] + bc[j]) * scale[r],
                                            &orow[t * 16 + m]);
            }
        }
    }
}

extern "C" void kernel_launch(void* const* d_in, const int* in_sizes, int n_in,
                              void* d_out, int out_size, void* d_ws, size_t ws_size,
                              hipStream_t stream) {
    const float* x    = (const float*)d_in[0];
    const int*   rows = (const int*)  d_in[1];
    const int*   cols = (const int*)  d_in[2];
    const float* vals = (const float*)d_in[3];
    const float* W    = (const float*)d_in[4];
    const float* b    = (const float*)d_in[5];
    float*       out  = (float*)d_out;

    const int Nn = in_sizes[0] / 128;    // 100000
    const int Ee = in_sizes[1];          // 1600000

    char*    ws      = (char*)d_ws;
    int*     row_ptr = (int*)ws;
    uint4*   Wf      = (uint4*)(ws + 448 * 1024);
    float*   xs      = (float*)(ws + 512 * 1024);
    u32x2_t* xq      = (u32x2_t*)(ws + 1024 * 1024);

    const int xcast_blks  = (Nn + 15) / 16;          // 6250 (16 rows/block)
    const int rowptr_blks = (Nn + 1 + 255) / 256;    // 391
    const int wcast_blks  = 16;

    prep_kernel<<<xcast_blks + rowptr_blks + wcast_blks, 256, 0, stream>>>(
        x, xq, xs, rows, row_ptr, W, Wf, Nn, Ee, xcast_blks, rowptr_blks);
    fused_kernel<<<(Nn + 15) / 16, 256, 0, stream>>>(
        row_ptr, cols, vals, x, xs, (const char*)xq,
        (const bf16x8_t*)Wf, b, out, Nn);
}